// Round 3
// baseline (774.267 us; speedup 1.0000x reference)
//
#include <hip/hip_runtime.h>
#include <cfloat>

#define B_    4
#define SNIP  8
#define CCH   256
#define HW    784
#define THW   6272      // SNIP*HW
#define NROWS 25088     // B_*THW
#define TOPK  5
#define NBLK  49        // THW/128
#define NPAIR 1225      // NBLK*(NBLK+1)/2

typedef _Float16 f16;
typedef f16   half8 __attribute__((ext_vector_type(8)));
typedef f16   half4 __attribute__((ext_vector_type(4)));
typedef float f32x4 __attribute__((ext_vector_type(4)));

// ---------------------------------------------------------------- utilities
__device__ __forceinline__ void ins5(float key, int idx, float tv[TOPK], int ti[TOPK]) {
    if (key > tv[4]) {
        if (key > tv[2]) {
            if (key > tv[1]) {
                tv[4] = tv[3]; ti[4] = ti[3];
                tv[3] = tv[2]; ti[3] = ti[2];
                tv[2] = tv[1]; ti[2] = ti[1];
                if (key > tv[0]) { tv[1] = tv[0]; ti[1] = ti[0]; tv[0] = key; ti[0] = idx; }
                else             { tv[1] = key;  ti[1] = idx; }
            } else {
                tv[4] = tv[3]; ti[4] = ti[3];
                tv[3] = tv[2]; ti[3] = ti[2];
                tv[2] = key;   ti[2] = idx;
            }
        } else {
            if (key > tv[3]) { tv[4] = tv[3]; ti[4] = ti[3]; tv[3] = key; ti[3] = idx; }
            else             { tv[4] = key;  ti[4] = idx; }
        }
    }
}

__device__ __forceinline__ void async16(const void* g, void* l) {
    __builtin_amdgcn_global_load_lds(
        (const __attribute__((address_space(1))) void*)g,
        (__attribute__((address_space(3))) void*)l, 16, 0, 0);
}

// ------------------------------------------------- 1. x[bs][c][p] -> xs[b][t][c]
__global__ __launch_bounds__(256)
void transpose_kernel(const float* __restrict__ x, float* __restrict__ xs) {
    __shared__ float T[32][33];
    const int bs = blockIdx.x;
    const int p0 = blockIdx.y * 32;
    const int c0 = blockIdx.z * 32;
    const int tx = threadIdx.x & 31, ty = threadIdx.x >> 5;
    const int b = bs >> 3, f = bs & 7;
#pragma unroll
    for (int q = 0; q < 4; ++q) {
        const int c = c0 + ty + 8 * q;
        const int p = p0 + tx;
        if (p < HW) T[ty + 8 * q][tx] = x[((size_t)bs * CCH + c) * HW + p];
    }
    __syncthreads();
#pragma unroll
    for (int q = 0; q < 4; ++q) {
        const int p = p0 + ty + 8 * q;
        if (p < HW)
            xs[((size_t)((size_t)b * THW + (size_t)f * HW + p)) * CCH + c0 + tx] = T[tx][ty + 8 * q];
    }
}

// ------------------------------------------------- 2. fp32 -> (hi,lo) f16 split
__global__ __launch_bounds__(256)
void split_kernel(const float* __restrict__ xs, f16* __restrict__ Xs) {
    const size_t i4 = ((size_t)blockIdx.x * 256 + threadIdx.x) * 4;
    const int row = (int)(i4 >> 8);
    const int c = (int)(i4 & 255);
    const float4 v = *(const float4*)(xs + i4);
    const f16 h0 = (f16)v.x, h1 = (f16)v.y, h2 = (f16)v.z, h3 = (f16)v.w;
    const f16 l0 = (f16)(v.x - (float)h0), l1 = (f16)(v.y - (float)h1);
    const f16 l2 = (f16)(v.z - (float)h2), l3 = (f16)(v.w - (float)h3);
    half4 hv; hv.x = h0; hv.y = h1; hv.z = h2; hv.w = h3;
    half4 lv; lv.x = l0; lv.y = l1; lv.z = l2; lv.w = l3;
    *(half4*)(Xs + (size_t)row * 512 + c) = hv;
    *(half4*)(Xs + (size_t)row * 512 + 256 + c) = lv;
}

// ------------------------------------------------- 3. per-row inverse norm
__global__ __launch_bounds__(256)
void rownorm_kernel(const float* __restrict__ xs, float* __restrict__ rinv) {
    const int tid = threadIdx.x;
    const int row = blockIdx.x * 4 + (tid >> 6);
    const int lane = tid & 63;
    const float4 v = *(const float4*)(xs + (size_t)row * CCH + lane * 4);
    float s = v.x * v.x + v.y * v.y + v.z * v.z + v.w * v.w;
#pragma unroll
    for (int m = 32; m >= 1; m >>= 1) s += __shfl_xor(s, m, 64);
    if (lane == 0) rinv[row] = 1.0f / sqrtf(s);
}

// ------------------------------------------------- 4. symmetric MFMA gram + dual-side partial top-5
// grid (1225, 4): pair (I,J), I>=J, of 128-row blocks; one 128x128 tile, K=768 virtual
// (f16 split: A-segs [hi,lo,hi], B-segs [hi,hi,lo]).
__global__ __launch_bounds__(256, 4)
void gram_sym_kernel(const f16* __restrict__ Xs, const float* __restrict__ rinv,
                     float* __restrict__ pval, unsigned char* __restrict__ pidx) {
    __shared__ __align__(16) char smem[32768];
    f16* As = (f16*)smem;                 // [128][64] halves, unit-swizzled
    f16* Bs = As + 8192;

    const int tid = threadIdx.x;
    const int lane = tid & 63, wid = tid >> 6;
    const int wr = (wid >> 1) * 64, wc = (wid & 1) * 64;
    const int lm = lane & 15, q = lane >> 4;
    const int lm7 = lm & 7;
    const int wp = wid >> 1;              // wave row-pair 0/1
    const int b = blockIdx.y;
    // pair decode
    const int p = blockIdx.x;
    int I = (int)((sqrtf(8.0f * p + 1.0f) - 1.0f) * 0.5f);
    while ((I + 1) * (I + 2) / 2 <= p) ++I;
    while (I * (I + 1) / 2 > p) --I;
    const int J = p - I * (I + 1) / 2;    // J <= I

    const size_t bbase = (size_t)b * THW;
    const f16* Xb = Xs + bbase * 512;
    const float* rvb = rinv + bbase;

    // staging lane map: row within pass, swizzled 16B-unit within row
    const int srow = tid >> 3;
    const int skk = (((tid & 7) ^ (srow & 7)) * 8);   // halves

    const int segA[3] = {0, 256, 0};
    const int segB[3] = {0, 0, 256};

    f32x4 acc[4][4];
#pragma unroll
    for (int i = 0; i < 4; ++i)
#pragma unroll
        for (int j = 0; j < 4; ++j) acc[i][j] = (f32x4)0.0f;

    for (int cc = 0; cc < 12; ++cc) {
        const int seg = cc >> 2, k64 = (cc & 3) * 64;
        const int aoff = segA[seg] + k64 + skk;
        const int boff = segB[seg] + k64 + skk;
#pragma unroll
        for (int p4 = 0; p4 < 4; ++p4)
            async16(Xb + (size_t)(I * 128 + srow + 32 * p4) * 512 + aoff,
                    smem + wid * 1024 + p4 * 4096);
#pragma unroll
        for (int p4 = 0; p4 < 4; ++p4)
            async16(Xb + (size_t)(J * 128 + srow + 32 * p4) * 512 + boff,
                    smem + 16384 + wid * 1024 + p4 * 4096);
        __syncthreads();
#pragma unroll
        for (int ks = 0; ks < 2; ++ks) {
            const int ku = (((4 * ks + q) ^ lm7) * 8);
            half8 av[4], bv[4];
#pragma unroll
            for (int i = 0; i < 4; ++i)
                av[i] = *(const half8*)(As + (wr + 16 * i + lm) * 64 + ku);
#pragma unroll
            for (int j = 0; j < 4; ++j)
                bv[j] = *(const half8*)(Bs + (wc + 16 * j + lm) * 64 + ku);
#pragma unroll
            for (int i = 0; i < 4; ++i)
#pragma unroll
                for (int j = 0; j < 4; ++j)
                    acc[i][j] = __builtin_amdgcn_mfma_f32_16x16x32_f16(av[i], bv[j], acc[i][j], 0, 0, 0);
        }
        __syncthreads();
    }

    // ---------------- J-side epilogue: columns of J ranked over rows of I ----------------
    {
        float tv[4][TOPK];
        int   ti[4][TOPK];
#pragma unroll
        for (int j = 0; j < 4; ++j)
#pragma unroll
            for (int s = 0; s < TOPK; ++s) { tv[j][s] = -FLT_MAX; ti[j][s] = 0; }
        int fj[4];
#pragma unroll
        for (int j = 0; j < 4; ++j) fj[j] = (J * 128 + wc + 16 * j + lm) / HW;
#pragma unroll
        for (int i = 0; i < 4; ++i) {
            const int tl = wr + 16 * i + 4 * q;          // local row
            const f32x4 r4 = *(const f32x4*)(rvb + I * 128 + tl);
#pragma unroll
            for (int reg = 0; reg < 4; ++reg) {
                const int ft = (I * 128 + tl + reg) / HW;
#pragma unroll
                for (int j = 0; j < 4; ++j) {
                    const float key = acc[i][j][reg] * r4[reg];
                    if (ft != fj[j]) ins5(key, tl + reg, tv[j], ti[j]);
                }
            }
        }
        // 8-slot merge per column through LDS (30.7KB, unioned with staging)
        float* Mv = (float*)smem;                       // [128][40]
        unsigned short* Mi = (unsigned short*)(smem + 20480);
        const int slot = wp * 4 + q;
#pragma unroll
        for (int j = 0; j < 4; ++j) {
            const int col = wc + 16 * j + lm;
#pragma unroll
            for (int s = 0; s < TOPK; ++s) {
                Mv[col * 40 + slot * 5 + s] = tv[j][s];
                Mi[col * 40 + slot * 5 + s] = (unsigned short)ti[j][s];
            }
        }
        __syncthreads();
        if (tid < 128) {
            float bv5[TOPK]; int bi5[TOPK];
#pragma unroll
            for (int s = 0; s < TOPK; ++s) { bv5[s] = -FLT_MAX; bi5[s] = 0; }
            for (int s = 0; s < 40; ++s) ins5(Mv[tid * 40 + s], (int)Mi[tid * 40 + s], bv5, bi5);
            const size_t base = ((bbase + J * 128 + tid) * NBLK + I) * TOPK;
#pragma unroll
            for (int s = 0; s < TOPK; ++s) { pval[base + s] = bv5[s]; pidx[base + s] = (unsigned char)bi5[s]; }
        }
    }

    // ---------------- I-side epilogue: columns of I ranked over rows of J ----------------
    if (I != J) {
        __syncthreads();
        float* Rv = (float*)smem;                       // [32][132] values
        float* Sv = (float*)(smem + 16896);             // [32][8][5]
        unsigned short* Si = (unsigned short*)(smem + 22016);
        float* rvJ = (float*)(smem + 24576);            // [128]
        if (tid < 128) rvJ[tid] = rvb[J * 128 + tid];
        // (barrier inside loop covers rvJ visibility before first scan)
#pragma unroll
        for (int ii = 0; ii < 4; ++ii) {
            // write phase: rows 16*ii block from both wave-pairs
            const int rr = wp * 16 + 4 * q;
#pragma unroll
            for (int reg = 0; reg < 4; ++reg)
#pragma unroll
                for (int j = 0; j < 4; ++j)
                    Rv[(rr + reg) * 132 + wc + 16 * j + lm] = acc[ii][j][reg];
            __syncthreads();
            // scan phase: 8 threads per row, 16 interleaved cols each
            const int rs = tid >> 3, k = tid & 7;
            const int rl = (rs >> 4) * 64 + 16 * ii + (rs & 15);
            const int ft = (I * 128 + rl) / HW;
            float sv[TOPK]; int si[TOPK];
#pragma unroll
            for (int s = 0; s < TOPK; ++s) { sv[s] = -FLT_MAX; si[s] = 0; }
            for (int ccol = 0; ccol < 16; ++ccol) {
                const int c = 8 * ccol + k;
                const int fc = (J * 128 + c) / HW;
                const float key = Rv[rs * 132 + c] * rvJ[c];
                if (fc != ft) ins5(key, c, sv, si);
            }
#pragma unroll
            for (int s = 0; s < TOPK; ++s) {
                Sv[(rs * 8 + k) * 5 + s] = sv[s];
                Si[(rs * 8 + k) * 5 + s] = (unsigned short)si[s];
            }
            __syncthreads();
            if (tid < 32) {
                const int rl2 = (tid >> 4) * 64 + 16 * ii + (tid & 15);
                float bv5[TOPK]; int bi5[TOPK];
#pragma unroll
                for (int s = 0; s < TOPK; ++s) { bv5[s] = -FLT_MAX; bi5[s] = 0; }
                for (int s = 0; s < 40; ++s) ins5(Sv[tid * 40 + s], (int)Si[tid * 40 + s], bv5, bi5);
                const size_t base = ((bbase + I * 128 + rl2) * NBLK + J) * TOPK;
#pragma unroll
                for (int s = 0; s < TOPK; ++s) { pval[base + s] = bv5[s]; pidx[base + s] = (unsigned char)bi5[s]; }
            }
            __syncthreads();
        }
    }
}

// ------------------------------------------------- 5. merge 49 partials per column
__global__ __launch_bounds__(64)
void merge_topk_kernel(const float* __restrict__ pval, const unsigned char* __restrict__ pidx,
                       int* __restrict__ idx5) {
    const int gid = blockIdx.x * 64 + threadIdx.x;    // 25088 columns (b*6272+c)
    float bv5[TOPK]; int bi5[TOPK];
#pragma unroll
    for (int s = 0; s < TOPK; ++s) { bv5[s] = -FLT_MAX; bi5[s] = 0; }
    const float* pv = pval + (size_t)gid * (NBLK * TOPK);
    const unsigned char* pi = pidx + (size_t)gid * (NBLK * TOPK);
    for (int o = 0; o < NBLK; ++o)
#pragma unroll
        for (int s = 0; s < TOPK; ++s) {
            const int e = o * TOPK + s;
            ins5(pv[e], o * 128 + (int)pi[e], bv5, bi5);
        }
    int* op = idx5 + (size_t)gid * TOPK;
#pragma unroll
    for (int s = 0; s < TOPK; ++s) op[s] = bi5[s];
}

// ------------------------------------------------- 6. gather (from f16 pair) + max + BN partials
__global__ __launch_bounds__(256)
void gather_bn_kernel(const f16* __restrict__ Xs, const int* __restrict__ idx5,
                      float* __restrict__ y, float* __restrict__ partial) {
    __shared__ float ls[2][4][256];
    const int tid = threadIdx.x;
    const int wid = tid >> 6, lane = tid & 63;
    const int row0 = blockIdx.x * 32 + wid * 8;
    float s1x = 0, s1y = 0, s1z = 0, s1w = 0;
    float s2x = 0, s2y = 0, s2z = 0, s2w = 0;
    for (int rr = 0; rr < 8; ++rr) {
        const int row = row0 + rr;
        const int b = row / THW;
        const int* id = idx5 + (size_t)row * TOPK;
        const f16* base = Xs + (size_t)b * THW * 512;
        float4 m = make_float4(-FLT_MAX, -FLT_MAX, -FLT_MAX, -FLT_MAX);
#pragma unroll
        for (int i = 0; i < TOPK; ++i) {
            const f16* rp = base + (size_t)id[i] * 512 + lane * 4;
            const half4 h = *(const half4*)rp;
            const half4 l = *(const half4*)(rp + 256);
            m.x = fmaxf(m.x, (float)h.x + (float)l.x);
            m.y = fmaxf(m.y, (float)h.y + (float)l.y);
            m.z = fmaxf(m.z, (float)h.z + (float)l.z);
            m.w = fmaxf(m.w, (float)h.w + (float)l.w);
        }
        *(float4*)(y + (size_t)row * CCH + lane * 4) = m;
        s1x += m.x; s1y += m.y; s1z += m.z; s1w += m.w;
        s2x += m.x * m.x; s2y += m.y * m.y; s2z += m.z * m.z; s2w += m.w * m.w;
    }
    *(float4*)&ls[0][wid][lane * 4] = make_float4(s1x, s1y, s1z, s1w);
    *(float4*)&ls[1][wid][lane * 4] = make_float4(s2x, s2y, s2z, s2w);
    __syncthreads();
    const float a  = ls[0][0][tid] + ls[0][1][tid] + ls[0][2][tid] + ls[0][3][tid];
    const float b2 = ls[1][0][tid] + ls[1][1][tid] + ls[1][2][tid] + ls[1][3][tid];
    partial[(size_t)blockIdx.x * 512 + tid] = a;
    partial[(size_t)blockIdx.x * 512 + 256 + tid] = b2;
}

// ------------------------------------------------- 7. BN finalize -> scale/shift
__global__ __launch_bounds__(256)
void bn_final_kernel(const float* __restrict__ partial, const float* __restrict__ gamma,
                     const float* __restrict__ beta, float* __restrict__ ab) {
    const int c = blockIdx.x;
    const int tid = threadIdx.x;
    float s1 = 0, s2 = 0;
    for (int p = tid; p < 784; p += 256) {
        s1 += partial[(size_t)p * 512 + c];
        s2 += partial[(size_t)p * 512 + 256 + c];
    }
    __shared__ float r1[256], r2[256];
    r1[tid] = s1; r2[tid] = s2;
    __syncthreads();
    for (int off = 128; off > 0; off >>= 1) {
        if (tid < off) { r1[tid] += r1[tid + off]; r2[tid] += r2[tid + off]; }
        __syncthreads();
    }
    if (tid == 0) {
        const float inv_n = 1.0f / 25088.0f;
        const float mean = r1[0] * inv_n;
        const float var  = r2[0] * inv_n - mean * mean;
        const float a = gamma[c] / sqrtf(var + 1e-5f);
        ab[c] = a;
        ab[256 + c] = beta[c] - mean * a;
    }
}

// ------------------------------------------------- 8. relu(BN) -> 1x1 conv + identity
#define TR 128
#define TJ 64
#define KC 64
__global__ __launch_bounds__(256, 2)
void conv_kernel(const float* __restrict__ y, const float* __restrict__ w,
                 const float* __restrict__ ab, const float* __restrict__ cb,
                 const float* __restrict__ x, float* __restrict__ out) {
    __shared__ float smem[(TR + TJ) * KC];
    float* As = smem;
    float* Bs = smem + TR * KC;
    const int tid = threadIdx.x;
    const int rt = blockIdx.x;
    const int o0 = blockIdx.y * TJ;
    const int rg = tid >> 4, cg = tid & 15;
    const int swa = rg & 7, swb = cg >> 1;
    const int sab16 = ((swa ^ swb) << 4);
    const int kqt = tid & 15, rbase = tid >> 4;

    float acc[8][4];
#pragma unroll
    for (int i = 0; i < 8; ++i)
#pragma unroll
        for (int j = 0; j < 4; ++j) acc[i][j] = 0.0f;

    for (int kc = 0; kc < CCH; kc += KC) {
        const int cbase = kc + 4 * kqt;
        const float4 sa = *(const float4*)(ab + cbase);
        const float4 sh = *(const float4*)(ab + 256 + cbase);
#pragma unroll
        for (int p = 0; p < 8; ++p) {
            const int r = rbase + 16 * p;
            const float4 v = *(const float4*)(y + (size_t)(rt * TR + r) * CCH + cbase);
            float4 z;
            z.x = fmaxf(fmaf(v.x, sa.x, sh.x), 0.0f);
            z.y = fmaxf(fmaf(v.y, sa.y, sh.y), 0.0f);
            z.z = fmaxf(fmaf(v.z, sa.z, sh.z), 0.0f);
            z.w = fmaxf(fmaf(v.w, sa.w, sh.w), 0.0f);
            *(float4*)(As + r * KC + 4 * (kqt ^ ((r >> 3) & 7))) = z;
        }
#pragma unroll
        for (int p = 0; p < 4; ++p) {
            const int r = rbase + 16 * p;
            const float4 v = *(const float4*)(w + (size_t)(o0 + r) * CCH + cbase);
            *(float4*)(Bs + r * KC + 4 * (kqt ^ ((r >> 3) & 7))) = v;
        }
        __syncthreads();
        const float* pa = As + rg * (8 * KC);
        const float* pb = Bs + cg * (4 * KC);
#pragma unroll 4
        for (int m = 0; m < 16; ++m) {
            float4 av[8];
#pragma unroll
            for (int i = 0; i < 8; ++i) av[i] = *(const float4*)(pa + i * KC + 4 * m);
            const float* pbm = (const float*)((const char*)pb + ((m << 4) ^ sab16));
            float4 bv[4];
#pragma unroll
            for (int j = 0; j < 4; ++j) bv[j] = *(const float4*)(pbm + j * KC);
#pragma unroll
            for (int i = 0; i < 8; ++i)
#pragma unroll
                for (int j = 0; j < 4; ++j) {
                    acc[i][j] = fmaf(av[i].x, bv[j].x, acc[i][j]);
                    acc[i][j] = fmaf(av[i].y, bv[j].y, acc[i][j]);
                    acc[i][j] = fmaf(av[i].z, bv[j].z, acc[i][j]);
                    acc[i][j] = fmaf(av[i].w, bv[j].w, acc[i][j]);
                }
        }
        __syncthreads();
    }
#pragma unroll
    for (int i = 0; i < 8; ++i) {
        const int R = rt * TR + 8 * rg + i;
        const int bs = R / HW;
        const int hw = R - bs * HW;
#pragma unroll
        for (int j = 0; j < 4; ++j) {
            const int o = o0 + 4 * cg + j;
            const size_t oi = ((size_t)bs * CCH + o) * HW + hw;
            out[oi] = acc[i][j] + cb[o] + x[oi];
        }
    }
}

// ------------------------------------------------- launch
extern "C" void kernel_launch(void* const* d_in, const int* in_sizes, int n_in,
                              void* d_out, int out_size, void* d_ws, size_t ws_size,
                              hipStream_t stream) {
    const float* x      = (const float*)d_in[0];
    const float* gamma  = (const float*)d_in[1];
    const float* beta   = (const float*)d_in[2];
    const float* conv_w = (const float*)d_in[3];
    const float* conv_b = (const float*)d_in[4];
    float* out = (float*)d_out;

    float* ws = (float*)d_ws;
    // Region A (6,422,528 floats): xs -> pval -> y (strictly sequential lifetimes)
    float* xs   = ws;
    float* pval = ws;                                  // [4*6272][49][5] = 6,146,560 floats
    float* y    = ws;
    f16*   Xsp  = (f16*)(ws + 6422528);                // 12,845,056 halves (25.7MB)
    float* rinv = ws + 12845056;                       // 25,088
    float* part = ws + 12870144;                       // 401,408
    float* ab   = ws + 13271552;                       // 512
    int*   idx5 = (int*)(ws + 13272064);               // 125,440 ints
    unsigned char* pidx = (unsigned char*)(ws + 13397504);  // 6,146,560 B
    // total = 14,934,144 floats = 59.7 MB

    transpose_kernel<<<dim3(32, 25, 8), 256, 0, stream>>>(x, xs);
    split_kernel<<<6272, 256, 0, stream>>>(xs, Xsp);
    rownorm_kernel<<<6272, 256, 0, stream>>>(xs, rinv);
    gram_sym_kernel<<<dim3(NPAIR, B_), 256, 0, stream>>>(Xsp, rinv, pval, pidx);
    merge_topk_kernel<<<NROWS / 64, 64, 0, stream>>>(pval, pidx, idx5);
    gather_bn_kernel<<<NROWS / 32, 256, 0, stream>>>(Xsp, idx5, y, part);
    bn_final_kernel<<<256, 256, 0, stream>>>(part, gamma, beta, ab);
    conv_kernel<<<dim3(NROWS / TR, CCH / TJ), 256, 0, stream>>>(y, conv_w, ab, conv_b, x, out);
}

// Round 4
// 640.035 us; speedup vs baseline: 1.2097x; 1.2097x over previous
//
#include <hip/hip_runtime.h>
#include <cfloat>

#define B_    4
#define SNIP  8
#define CCH   256
#define HW    784
#define THW   6272      // SNIP*HW
#define NROWS 25088     // B_*THW
#define TOPK  5
#define NRG   13        // row-tile groups (49 tiles strided by 13 -> 3..4 tiles/block)

typedef _Float16 f16;
typedef f16   half8 __attribute__((ext_vector_type(8)));
typedef f16   half4 __attribute__((ext_vector_type(4)));
typedef float f32x4 __attribute__((ext_vector_type(4)));

// ---------------------------------------------------------------- utilities
__device__ __forceinline__ void ins5(float key, int idx, float tv[TOPK], int ti[TOPK]) {
    if (key > tv[4]) {
        if (key > tv[2]) {
            if (key > tv[1]) {
                tv[4] = tv[3]; ti[4] = ti[3];
                tv[3] = tv[2]; ti[3] = ti[2];
                tv[2] = tv[1]; ti[2] = ti[1];
                if (key > tv[0]) { tv[1] = tv[0]; ti[1] = ti[0]; tv[0] = key; ti[0] = idx; }
                else             { tv[1] = key;  ti[1] = idx; }
            } else {
                tv[4] = tv[3]; ti[4] = ti[3];
                tv[3] = tv[2]; ti[3] = ti[2];
                tv[2] = key;   ti[2] = idx;
            }
        } else {
            if (key > tv[3]) { tv[4] = tv[3]; ti[4] = ti[3]; tv[3] = key; ti[3] = idx; }
            else             { tv[4] = key;  ti[4] = idx; }
        }
    }
}

// top-5 insert with indices packed 2-per-register (16-bit fields; sh = 0 or 16)
#define TI_MOVE(s) tip[s] = (tip[s] & ~fm) | (tip[s-1] & fm)
#define TI_SET(s)  tip[s] = (tip[s] & ~fm) | ((unsigned)idx << sh)
__device__ __forceinline__ void ins5p(float key, int idx, float tv[TOPK],
                                      unsigned tip[TOPK], const int sh) {
    const unsigned fm = 0xFFFFu << sh;
    if (key > tv[4]) {
        if (key > tv[2]) {
            if (key > tv[1]) {
                tv[4] = tv[3]; TI_MOVE(4);
                tv[3] = tv[2]; TI_MOVE(3);
                tv[2] = tv[1]; TI_MOVE(2);
                if (key > tv[0]) { tv[1] = tv[0]; TI_MOVE(1); tv[0] = key; TI_SET(0); }
                else             { tv[1] = key;  TI_SET(1); }
            } else {
                tv[4] = tv[3]; TI_MOVE(4);
                tv[3] = tv[2]; TI_MOVE(3);
                tv[2] = key;   TI_SET(2);
            }
        } else {
            if (key > tv[3]) { tv[4] = tv[3]; TI_MOVE(4); tv[3] = key; TI_SET(3); }
            else             { tv[4] = key;  TI_SET(4); }
        }
    }
}

__device__ __forceinline__ void async16(const void* g, void* l) {
    __builtin_amdgcn_global_load_lds(
        (const __attribute__((address_space(1))) void*)g,
        (__attribute__((address_space(3))) void*)l, 16, 0, 0);
}

// ------------------------------------------------- 1. x[bs][c][p] -> hi/lo f16 planes
__global__ __launch_bounds__(256)
void transpose_split_kernel(const float* __restrict__ x, f16* __restrict__ Xs) {
    __shared__ float T[32][33];
    const int bs = blockIdx.x;
    const int p0 = blockIdx.y * 32;
    const int c0 = blockIdx.z * 32;
    const int tx = threadIdx.x & 31, ty = threadIdx.x >> 5;
    const int b = bs >> 3, f = bs & 7;
#pragma unroll
    for (int q = 0; q < 4; ++q) {
        const int c = c0 + ty + 8 * q;
        const int p = p0 + tx;
        if (p < HW) T[ty + 8 * q][tx] = x[((size_t)bs * CCH + c) * HW + p];
    }
    __syncthreads();
#pragma unroll
    for (int q = 0; q < 4; ++q) {
        const int p = p0 + ty + 8 * q;
        if (p < HW) {
            const size_t row = (size_t)b * THW + (size_t)f * HW + p;
            const float v = T[tx][ty + 8 * q];
            const f16 h = (f16)v;
            const f16 l = (f16)(v - (float)h);
            Xs[row * 512 + c0 + tx] = h;
            Xs[row * 512 + 256 + c0 + tx] = l;
        }
    }
}

// ------------------------------------------------- 2. per-row inverse norm (from hi+lo)
__global__ __launch_bounds__(256)
void rownorm_kernel(const f16* __restrict__ Xs, float* __restrict__ rinv) {
    const int tid = threadIdx.x;
    const int row = blockIdx.x * 4 + (tid >> 6);
    const int lane = tid & 63;
    const half4 h = *(const half4*)(Xs + (size_t)row * 512 + lane * 4);
    const half4 l = *(const half4*)(Xs + (size_t)row * 512 + 256 + lane * 4);
    const float v0 = (float)h.x + (float)l.x, v1 = (float)h.y + (float)l.y;
    const float v2 = (float)h.z + (float)l.z, v3 = (float)h.w + (float)l.w;
    float s = v0 * v0 + v1 * v1 + v2 * v2 + v3 * v3;
#pragma unroll
    for (int m = 32; m >= 1; m >>= 1) s += __shfl_xor(s, m, 64);
    if (lane == 0) rinv[row] = 1.0f / sqrtf(s);
}

// ------------------------------------------------- 3. MFMA gram + partial top-5
// grid (49, 13, 4): 128-col block, row tiles rt = rg, rg+13, ... (<49), virtual K=768
// (f16 split: A-segs [hi,lo,hi], B-segs [hi,hi,lo]).
__global__ __launch_bounds__(256, 4)
void gram_mfma_kernel(const f16* __restrict__ Xs, const float* __restrict__ rinv,
                      float* __restrict__ pval, unsigned short* __restrict__ pidx) {
    __shared__ __align__(16) char smem[32768];   // staging 32KB | merge 30KB (reused)
    f16* As = (f16*)smem;                 // [128][64] halves, unit-swizzled
    f16* Bs = As + 8192;

    const int tid = threadIdx.x;
    const int lane = tid & 63, wid = tid >> 6;
    const int wr = (wid >> 1) * 64, wc = (wid & 1) * 64;
    const int lm = lane & 15, q = lane >> 4;
    const int lm7 = lm & 7;
    const int b = blockIdx.z;
    const int j0 = blockIdx.x * 128;
    const int rg = blockIdx.y;
    const size_t bbase = (size_t)b * THW;
    const f16* Xb = Xs + bbase * 512;
    const float* rvb = rinv + bbase;

    // staging lane map: row within pass, swizzled 16B-unit within row
    const int srow = tid >> 3;
    const int skk = (((tid & 7) ^ (srow & 7)) * 8);   // halves

    int fj[4];
#pragma unroll
    for (int j = 0; j < 4; ++j) fj[j] = (j0 + wc + 16 * j + lm) / HW;

    float tv[4][TOPK];
    unsigned tip[2][TOPK];
#pragma unroll
    for (int j = 0; j < 4; ++j)
#pragma unroll
        for (int s = 0; s < TOPK; ++s) tv[j][s] = -FLT_MAX;
#pragma unroll
    for (int jp = 0; jp < 2; ++jp)
#pragma unroll
        for (int s = 0; s < TOPK; ++s) tip[jp][s] = 0u;

    const int segA[3] = {0, 256, 0};
    const int segB[3] = {0, 0, 256};

    for (int rt = rg; rt < 49; rt += NRG) {
        const int t0 = rt * 128;
        f32x4 acc[4][4];
#pragma unroll
        for (int i = 0; i < 4; ++i)
#pragma unroll
            for (int j = 0; j < 4; ++j) acc[i][j] = (f32x4)0.0f;

        for (int cc = 0; cc < 12; ++cc) {
            const int seg = cc >> 2, k64 = (cc & 3) * 64;
            const int aoff = segA[seg] + k64 + skk;
            const int boff = segB[seg] + k64 + skk;
#pragma unroll
            for (int p4 = 0; p4 < 4; ++p4)
                async16(Xb + (size_t)(t0 + srow + 32 * p4) * 512 + aoff,
                        smem + wid * 1024 + p4 * 4096);
#pragma unroll
            for (int p4 = 0; p4 < 4; ++p4)
                async16(Xb + (size_t)(j0 + srow + 32 * p4) * 512 + boff,
                        smem + 16384 + wid * 1024 + p4 * 4096);
            __syncthreads();
#pragma unroll
            for (int ks = 0; ks < 2; ++ks) {
                const int ku = (((4 * ks + q) ^ lm7) * 8);
                half8 av[4], bv[4];
#pragma unroll
                for (int i = 0; i < 4; ++i)
                    av[i] = *(const half8*)(As + (wr + 16 * i + lm) * 64 + ku);
#pragma unroll
                for (int j = 0; j < 4; ++j)
                    bv[j] = *(const half8*)(Bs + (wc + 16 * j + lm) * 64 + ku);
#pragma unroll
                for (int i = 0; i < 4; ++i)
#pragma unroll
                    for (int j = 0; j < 4; ++j)
                        acc[i][j] = __builtin_amdgcn_mfma_f32_16x16x32_f16(av[i], bv[j], acc[i][j], 0, 0, 0);
            }
            __syncthreads();
        }
        // epilogue: key = up * rinv[row]; mask same-frame; private top-5 (registers only)
#pragma unroll
        for (int i = 0; i < 4; ++i) {
            const int tb = t0 + wr + 16 * i + 4 * q;
            const f32x4 r4 = *(const f32x4*)(rvb + tb);
#pragma unroll
            for (int reg = 0; reg < 4; ++reg) {
                const int t = tb + reg;
                const int ft = t / HW;
#pragma unroll
                for (int j = 0; j < 4; ++j) {
                    const float key = acc[i][j][reg] * r4[reg];
                    if (ft != fj[j]) ins5p(key, t, tv[j], tip[j >> 1], (j & 1) * 16);
                }
            }
        }
    }

    // merge: per column (128), 8 contributor slots (2 wave-pairs x 4 q) x 5 entries
    float* Mv = (float*)smem;                       // [128][40] = 20KB
    unsigned short* Mi = (unsigned short*)(smem + 20480);   // [128][40] = 10KB
    const int slot = (wid >> 1) * 4 + q;
#pragma unroll
    for (int j = 0; j < 4; ++j) {
        const int col = wc + 16 * j + lm;
        const int sh = (j & 1) * 16;
#pragma unroll
        for (int s = 0; s < TOPK; ++s) {
            Mv[col * 40 + slot * 5 + s] = tv[j][s];
            Mi[col * 40 + slot * 5 + s] = (unsigned short)((tip[j >> 1][s] >> sh) & 0xFFFFu);
        }
    }
    __syncthreads();
    if (tid < 128) {
        float bv5[TOPK]; int bi5[TOPK];
#pragma unroll
        for (int s = 0; s < TOPK; ++s) { bv5[s] = -FLT_MAX; bi5[s] = 0; }
        for (int s = 0; s < 40; ++s) ins5(Mv[tid * 40 + s], (int)Mi[tid * 40 + s], bv5, bi5);
        // layout [rg][col_global][5] -> coalesced writes across tid
        const size_t base = ((size_t)rg * NROWS + bbase + j0 + tid) * TOPK;
#pragma unroll
        for (int s = 0; s < TOPK; ++s) { pval[base + s] = bv5[s]; pidx[base + s] = (unsigned short)bi5[s]; }
    }
}

// ------------------------------------------------- 4. merge 13 row-group partials per column
__global__ __launch_bounds__(64)
void merge_topk_kernel(const float* __restrict__ pval, const unsigned short* __restrict__ pidx,
                       int* __restrict__ idx5) {
    const int gid = blockIdx.x * 64 + threadIdx.x;    // 25088 columns (b*6272+c)
    float bv5[TOPK]; int bi5[TOPK];
#pragma unroll
    for (int s = 0; s < TOPK; ++s) { bv5[s] = -FLT_MAX; bi5[s] = 0; }
    for (int g = 0; g < NRG; ++g) {
        const size_t base = ((size_t)g * NROWS + gid) * TOPK;
#pragma unroll
        for (int s = 0; s < TOPK; ++s)
            ins5(pval[base + s], (int)pidx[base + s], bv5, bi5);
    }
    int* op = idx5 + (size_t)gid * TOPK;
#pragma unroll
    for (int s = 0; s < TOPK; ++s) op[s] = bi5[s];
}

// ------------------------------------------------- 5. gather (from f16 pair) + max + BN partials
__global__ __launch_bounds__(256)
void gather_bn_kernel(const f16* __restrict__ Xs, const int* __restrict__ idx5,
                      float* __restrict__ y, float* __restrict__ partial) {
    __shared__ float ls[2][4][256];
    const int tid = threadIdx.x;
    const int wid = tid >> 6, lane = tid & 63;
    const int row0 = blockIdx.x * 32 + wid * 8;
    float s1x = 0, s1y = 0, s1z = 0, s1w = 0;
    float s2x = 0, s2y = 0, s2z = 0, s2w = 0;
    for (int rr = 0; rr < 8; ++rr) {
        const int row = row0 + rr;
        const int b = row / THW;
        const int* id = idx5 + (size_t)row * TOPK;
        const f16* base = Xs + (size_t)b * THW * 512;
        float4 m = make_float4(-FLT_MAX, -FLT_MAX, -FLT_MAX, -FLT_MAX);
#pragma unroll
        for (int i = 0; i < TOPK; ++i) {
            const f16* rp = base + (size_t)id[i] * 512 + lane * 4;
            const half4 h = *(const half4*)rp;
            const half4 l = *(const half4*)(rp + 256);
            m.x = fmaxf(m.x, (float)h.x + (float)l.x);
            m.y = fmaxf(m.y, (float)h.y + (float)l.y);
            m.z = fmaxf(m.z, (float)h.z + (float)l.z);
            m.w = fmaxf(m.w, (float)h.w + (float)l.w);
        }
        *(float4*)(y + (size_t)row * CCH + lane * 4) = m;
        s1x += m.x; s1y += m.y; s1z += m.z; s1w += m.w;
        s2x += m.x * m.x; s2y += m.y * m.y; s2z += m.z * m.z; s2w += m.w * m.w;
    }
    *(float4*)&ls[0][wid][lane * 4] = make_float4(s1x, s1y, s1z, s1w);
    *(float4*)&ls[1][wid][lane * 4] = make_float4(s2x, s2y, s2z, s2w);
    __syncthreads();
    const float a  = ls[0][0][tid] + ls[0][1][tid] + ls[0][2][tid] + ls[0][3][tid];
    const float b2 = ls[1][0][tid] + ls[1][1][tid] + ls[1][2][tid] + ls[1][3][tid];
    partial[(size_t)blockIdx.x * 512 + tid] = a;
    partial[(size_t)blockIdx.x * 512 + 256 + tid] = b2;
}

// ------------------------------------------------- 6. BN finalize -> scale/shift
__global__ __launch_bounds__(256)
void bn_final_kernel(const float* __restrict__ partial, const float* __restrict__ gamma,
                     const float* __restrict__ beta, float* __restrict__ ab) {
    const int c = blockIdx.x;
    const int tid = threadIdx.x;
    float s1 = 0, s2 = 0;
    for (int p = tid; p < 784; p += 256) {
        s1 += partial[(size_t)p * 512 + c];
        s2 += partial[(size_t)p * 512 + 256 + c];
    }
    __shared__ float r1[256], r2[256];
    r1[tid] = s1; r2[tid] = s2;
    __syncthreads();
    for (int off = 128; off > 0; off >>= 1) {
        if (tid < off) { r1[tid] += r1[tid + off]; r2[tid] += r2[tid + off]; }
        __syncthreads();
    }
    if (tid == 0) {
        const float inv_n = 1.0f / 25088.0f;
        const float mean = r1[0] * inv_n;
        const float var  = r2[0] * inv_n - mean * mean;
        const float a = gamma[c] / sqrtf(var + 1e-5f);
        ab[c] = a;
        ab[256 + c] = beta[c] - mean * a;
    }
}

// ------------------------------------------------- 7. relu(BN) -> 1x1 conv + identity
#define TR 128
#define TJ 64
#define KC 64
__global__ __launch_bounds__(256, 2)
void conv_kernel(const float* __restrict__ y, const float* __restrict__ w,
                 const float* __restrict__ ab, const float* __restrict__ cb,
                 const float* __restrict__ x, float* __restrict__ out) {
    __shared__ float smem[(TR + TJ) * KC];
    float* As = smem;
    float* Bs = smem + TR * KC;
    const int tid = threadIdx.x;
    const int rt = blockIdx.x;
    const int o0 = blockIdx.y * TJ;
    const int rg = tid >> 4, cg = tid & 15;
    const int swa = rg & 7, swb = cg >> 1;
    const int sab16 = ((swa ^ swb) << 4);
    const int kqt = tid & 15, rbase = tid >> 4;

    float acc[8][4];
#pragma unroll
    for (int i = 0; i < 8; ++i)
#pragma unroll
        for (int j = 0; j < 4; ++j) acc[i][j] = 0.0f;

    for (int kc = 0; kc < CCH; kc += KC) {
        const int cbase = kc + 4 * kqt;
        const float4 sa = *(const float4*)(ab + cbase);
        const float4 sh = *(const float4*)(ab + 256 + cbase);
#pragma unroll
        for (int p = 0; p < 8; ++p) {
            const int r = rbase + 16 * p;
            const float4 v = *(const float4*)(y + (size_t)(rt * TR + r) * CCH + cbase);
            float4 z;
            z.x = fmaxf(fmaf(v.x, sa.x, sh.x), 0.0f);
            z.y = fmaxf(fmaf(v.y, sa.y, sh.y), 0.0f);
            z.z = fmaxf(fmaf(v.z, sa.z, sh.z), 0.0f);
            z.w = fmaxf(fmaf(v.w, sa.w, sh.w), 0.0f);
            *(float4*)(As + r * KC + 4 * (kqt ^ ((r >> 3) & 7))) = z;
        }
#pragma unroll
        for (int p = 0; p < 4; ++p) {
            const int r = rbase + 16 * p;
            const float4 v = *(const float4*)(w + (size_t)(o0 + r) * CCH + cbase);
            *(float4*)(Bs + r * KC + 4 * (kqt ^ ((r >> 3) & 7))) = v;
        }
        __syncthreads();
        const float* pa = As + rg * (8 * KC);
        const float* pb = Bs + cg * (4 * KC);
#pragma unroll 4
        for (int m = 0; m < 16; ++m) {
            float4 av[8];
#pragma unroll
            for (int i = 0; i < 8; ++i) av[i] = *(const float4*)(pa + i * KC + 4 * m);
            const float* pbm = (const float*)((const char*)pb + ((m << 4) ^ sab16));
            float4 bv[4];
#pragma unroll
            for (int j = 0; j < 4; ++j) bv[j] = *(const float4*)(pbm + j * KC);
#pragma unroll
            for (int i = 0; i < 8; ++i)
#pragma unroll
                for (int j = 0; j < 4; ++j) {
                    acc[i][j] = fmaf(av[i].x, bv[j].x, acc[i][j]);
                    acc[i][j] = fmaf(av[i].y, bv[j].y, acc[i][j]);
                    acc[i][j] = fmaf(av[i].z, bv[j].z, acc[i][j]);
                    acc[i][j] = fmaf(av[i].w, bv[j].w, acc[i][j]);
                }
        }
        __syncthreads();
    }
#pragma unroll
    for (int i = 0; i < 8; ++i) {
        const int R = rt * TR + 8 * rg + i;
        const int bs = R / HW;
        const int hw = R - bs * HW;
#pragma unroll
        for (int j = 0; j < 4; ++j) {
            const int o = o0 + 4 * cg + j;
            const size_t oi = ((size_t)bs * CCH + o) * HW + hw;
            out[oi] = acc[i][j] + cb[o] + x[oi];
        }
    }
}

// ------------------------------------------------- launch
extern "C" void kernel_launch(void* const* d_in, const int* in_sizes, int n_in,
                              void* d_out, int out_size, void* d_ws, size_t ws_size,
                              hipStream_t stream) {
    const float* x      = (const float*)d_in[0];
    const float* gamma  = (const float*)d_in[1];
    const float* beta   = (const float*)d_in[2];
    const float* conv_w = (const float*)d_in[3];
    const float* conv_b = (const float*)d_in[4];
    float* out = (float*)d_out;

    float* ws = (float*)d_ws;
    f16*   Xsp  = (f16*)ws;                            // 12,845,056 halves (25.7MB)
    // Region B (6,422,528 floats): pval+pidx -> y (sequential lifetimes)
    float* yreg = ws + 6422528;
    float* pval = yreg;                                // [13][25088][5] = 1,630,720 f
    unsigned short* pidx = (unsigned short*)(yreg + 1630720);  // same count, ushort
    float* y    = yreg;
    float* rinv = ws + 12845056;                       // 25,088
    float* part = ws + 12870144;                       // 401,408
    float* ab   = ws + 13271552;                       // 512
    int*   idx5 = (int*)(ws + 13272064);               // 125,440 ints
    // total = 13,397,504 floats = 53.6 MB

    transpose_split_kernel<<<dim3(32, 25, 8), 256, 0, stream>>>(x, Xsp);
    rownorm_kernel<<<6272, 256, 0, stream>>>(Xsp, rinv);
    gram_mfma_kernel<<<dim3(49, NRG, B_), 256, 0, stream>>>(Xsp, rinv, pval, pidx);
    merge_topk_kernel<<<NROWS / 64, 64, 0, stream>>>(pval, pidx, idx5);
    gather_bn_kernel<<<NROWS / 32, 256, 0, stream>>>(Xsp, idx5, y, part);
    bn_final_kernel<<<256, 256, 0, stream>>>(part, gamma, beta, ab);
    conv_kernel<<<dim3(NROWS / TR, CCH / TJ), 256, 0, stream>>>(y, conv_w, ab, conv_b, x, out);
}

// Round 5
// 551.031 us; speedup vs baseline: 1.4051x; 1.1615x over previous
//
#include <hip/hip_runtime.h>
#include <cfloat>

#define B_    4
#define SNIP  8
#define CCH   256
#define HW    784
#define THW   6272      // SNIP*HW
#define NROWS 25088     // B_*THW
#define TOPK  5

typedef _Float16 f16;
typedef f16   half8 __attribute__((ext_vector_type(8)));
typedef f16   half4 __attribute__((ext_vector_type(4)));
typedef float f32x4 __attribute__((ext_vector_type(4)));

// ---------------------------------------------------------------- utilities
__device__ __forceinline__ void ins5(float key, int idx, float tv[TOPK], int ti[TOPK]) {
    if (key > tv[4]) {
        if (key > tv[2]) {
            if (key > tv[1]) {
                tv[4] = tv[3]; ti[4] = ti[3];
                tv[3] = tv[2]; ti[3] = ti[2];
                tv[2] = tv[1]; ti[2] = ti[1];
                if (key > tv[0]) { tv[1] = tv[0]; ti[1] = ti[0]; tv[0] = key; ti[0] = idx; }
                else             { tv[1] = key;  ti[1] = idx; }
            } else {
                tv[4] = tv[3]; ti[4] = ti[3];
                tv[3] = tv[2]; ti[3] = ti[2];
                tv[2] = key;   ti[2] = idx;
            }
        } else {
            if (key > tv[3]) { tv[4] = tv[3]; ti[4] = ti[3]; tv[3] = key; ti[3] = idx; }
            else             { tv[4] = key;  ti[4] = idx; }
        }
    }
}

__device__ __forceinline__ void async16(const void* g, void* l) {
    __builtin_amdgcn_global_load_lds(
        (const __attribute__((address_space(1))) void*)g,
        (__attribute__((address_space(3))) void*)l, 16, 0, 0);
}

// ------------------------------------------------- 1. x[bs][c][p] -> hi/lo f16 planes
__global__ __launch_bounds__(256)
void transpose_split_kernel(const float* __restrict__ x, f16* __restrict__ Xs) {
    __shared__ float T[32][33];
    const int bs = blockIdx.x;
    const int p0 = blockIdx.y * 32;
    const int c0 = blockIdx.z * 32;
    const int tx = threadIdx.x & 31, ty = threadIdx.x >> 5;
    const int b = bs >> 3, f = bs & 7;
#pragma unroll
    for (int q = 0; q < 4; ++q) {
        const int c = c0 + ty + 8 * q;
        const int p = p0 + tx;
        if (p < HW) T[ty + 8 * q][tx] = x[((size_t)bs * CCH + c) * HW + p];
    }
    __syncthreads();
#pragma unroll
    for (int q = 0; q < 4; ++q) {
        const int p = p0 + ty + 8 * q;
        if (p < HW) {
            const size_t row = (size_t)b * THW + (size_t)f * HW + p;
            const float v = T[tx][ty + 8 * q];
            const f16 h = (f16)v;
            const f16 l = (f16)(v - (float)h);
            Xs[row * 512 + c0 + tx] = h;
            Xs[row * 512 + 256 + c0 + tx] = l;
        }
    }
}

// ------------------------------------------------- 2. per-row inverse norm (from hi+lo)
__global__ __launch_bounds__(256)
void rownorm_kernel(const f16* __restrict__ Xs, float* __restrict__ rinv) {
    const int tid = threadIdx.x;
    const int row = blockIdx.x * 4 + (tid >> 6);
    const int lane = tid & 63;
    const half4 h = *(const half4*)(Xs + (size_t)row * 512 + lane * 4);
    const half4 l = *(const half4*)(Xs + (size_t)row * 512 + 256 + lane * 4);
    const float v0 = (float)h.x + (float)l.x, v1 = (float)h.y + (float)l.y;
    const float v2 = (float)h.z + (float)l.z, v3 = (float)h.w + (float)l.w;
    float s = v0 * v0 + v1 * v1 + v2 * v2 + v3 * v3;
#pragma unroll
    for (int m = 32; m >= 1; m >>= 1) s += __shfl_xor(s, m, 64);
    if (lane == 0) rinv[row] = 1.0f / sqrtf(s);
}

// ------------------------------------------------- 3. MFMA gram + partial top-5 (r2-verbatim)
// grid (49, 7, 4). Per block: 128-col block, 7 row-tiles of 128, virtual K=768
// (f16 split: segments A=[hi,lo,hi], B=[hi,hi,lo]).
__global__ __launch_bounds__(256, 2)
void gram_mfma_kernel(const f16* __restrict__ Xs, const float* __restrict__ rinv,
                      float* __restrict__ pval, int* __restrict__ pidx) {
    __shared__ char smem[40960];          // staging 32KB  |  merge 40KB (reused)
    f16* As = (f16*)smem;                 // [128][64] halves, unit-swizzled
    f16* Bs = As + 8192;

    const int tid = threadIdx.x;
    const int lane = tid & 63, wid = tid >> 6;
    const int wr = (wid >> 1) * 64, wc = (wid & 1) * 64;
    const int lm = lane & 15, q = lane >> 4;
    const int lm7 = lm & 7;
    const int b = blockIdx.z;
    const int j0 = blockIdx.x * 128;
    const int rg = blockIdx.y;
    const size_t bbase = (size_t)b * THW;
    const f16* Xb = Xs + bbase * 512;
    const float* rv = rinv + bbase;

    // staging lane map: row within pass, swizzled 16B-unit within row
    const int srow = tid >> 3;
    const int skk = (((tid & 7) ^ (srow & 7)) * 8);   // halves

    int fj[4];
#pragma unroll
    for (int j = 0; j < 4; ++j) fj[j] = (j0 + wc + 16 * j + lm) / HW;

    float tv[4][TOPK];
    int   ti[4][TOPK];
#pragma unroll
    for (int j = 0; j < 4; ++j)
#pragma unroll
        for (int s = 0; s < TOPK; ++s) { tv[j][s] = -FLT_MAX; ti[j][s] = 0; }

    const int segA[3] = {0, 256, 0};
    const int segB[3] = {0, 0, 256};

    for (int it = 0; it < 7; ++it) {
        const int t0 = (rg * 7 + it) * 128;
        f32x4 acc[4][4];
#pragma unroll
        for (int i = 0; i < 4; ++i)
#pragma unroll
            for (int j = 0; j < 4; ++j) acc[i][j] = (f32x4)0.0f;

        for (int cc = 0; cc < 12; ++cc) {
            const int seg = cc >> 2, k64 = (cc & 3) * 64;
            const int aoff = segA[seg] + k64 + skk;
            const int boff = segB[seg] + k64 + skk;
#pragma unroll
            for (int p = 0; p < 4; ++p)
                async16(Xb + (size_t)(t0 + srow + 32 * p) * 512 + aoff,
                        smem + wid * 1024 + p * 4096);
#pragma unroll
            for (int p = 0; p < 4; ++p)
                async16(Xb + (size_t)(j0 + srow + 32 * p) * 512 + boff,
                        smem + 16384 + wid * 1024 + p * 4096);
            __syncthreads();
#pragma unroll
            for (int ks = 0; ks < 2; ++ks) {
                const int ku = (((4 * ks + q) ^ lm7) * 8);   // swizzled unit, halves
                half8 av[4], bv[4];
#pragma unroll
                for (int i = 0; i < 4; ++i)
                    av[i] = *(const half8*)(As + (wr + 16 * i + lm) * 64 + ku);
#pragma unroll
                for (int j = 0; j < 4; ++j)
                    bv[j] = *(const half8*)(Bs + (wc + 16 * j + lm) * 64 + ku);
#pragma unroll
                for (int i = 0; i < 4; ++i)
#pragma unroll
                    for (int j = 0; j < 4; ++j)
                        acc[i][j] = __builtin_amdgcn_mfma_f32_16x16x32_f16(av[i], bv[j], acc[i][j], 0, 0, 0);
            }
            __syncthreads();
        }
        // epilogue: key = up * rinv[row]; mask same-frame; private top-5
#pragma unroll
        for (int i = 0; i < 4; ++i) {
            const int tb = t0 + wr + 16 * i + 4 * q;
            const f32x4 r4 = *(const f32x4*)(rv + tb);
#pragma unroll
            for (int reg = 0; reg < 4; ++reg) {
                const int t = tb + reg;
                const int ft = t / HW;
#pragma unroll
                for (int j = 0; j < 4; ++j) {
                    const float key = acc[i][j][reg] * r4[reg];
                    if (ft != fj[j]) ins5(key, t, tv[j], ti[j]);
                }
            }
        }
    }

    // merge: per column (128), 8 contributor slots (2 waves x 4 q) x 5 entries
    __syncthreads();
    float* Mv = (float*)smem;                  // 128*8*5 = 5120 floats (20KB)
    int*   Mi = (int*)(smem + 20480);
    const int slot = (wid >> 1) * 4 + q;
#pragma unroll
    for (int j = 0; j < 4; ++j) {
        const int c128 = wc + 16 * j + lm;
#pragma unroll
        for (int s = 0; s < TOPK; ++s) {
            Mv[(c128 * 8 + slot) * TOPK + s] = tv[j][s];
            Mi[(c128 * 8 + slot) * TOPK + s] = ti[j][s];
        }
    }
    __syncthreads();
    if (tid < 128) {
        float bv5[TOPK]; int bi5[TOPK];
#pragma unroll
        for (int s = 0; s < TOPK; ++s) { bv5[s] = -FLT_MAX; bi5[s] = 0; }
        for (int s = 0; s < 40; ++s) ins5(Mv[tid * 40 + s], Mi[tid * 40 + s], bv5, bi5);
        const size_t base = ((bbase + j0 + tid) * 7 + rg) * TOPK;
#pragma unroll
        for (int s = 0; s < TOPK; ++s) { pval[base + s] = bv5[s]; pidx[base + s] = bi5[s]; }
    }
}

// ------------------------------------------------- 4. merge row-group partials
__global__ __launch_bounds__(256)
void merge_topk_kernel(const float* __restrict__ pval, const int* __restrict__ pidx,
                       int* __restrict__ idx5) {
    const int gid = blockIdx.x * 256 + threadIdx.x;   // 25088 columns
    float bv5[TOPK]; int bi5[TOPK];
#pragma unroll
    for (int s = 0; s < TOPK; ++s) { bv5[s] = -FLT_MAX; bi5[s] = 0; }
    const float* pv = pval + (size_t)gid * 35;
    const int* pi = pidx + (size_t)gid * 35;
    for (int s = 0; s < 35; ++s) ins5(pv[s], pi[s], bv5, bi5);
    int* op = idx5 + (size_t)gid * TOPK;
#pragma unroll
    for (int s = 0; s < TOPK; ++s) op[s] = bi5[s];
}

// ------------------------------------------------- 5. gather (from f16 pair) + max -> y f16 + BN partials
__global__ __launch_bounds__(256)
void gather_bn_kernel(const f16* __restrict__ Xs, const int* __restrict__ idx5,
                      f16* __restrict__ yf, float* __restrict__ partial) {
    __shared__ float ls[2][4][256];
    const int tid = threadIdx.x;
    const int wid = tid >> 6, lane = tid & 63;
    const int row0 = blockIdx.x * 32 + wid * 8;
    float s1x = 0, s1y = 0, s1z = 0, s1w = 0;
    float s2x = 0, s2y = 0, s2z = 0, s2w = 0;
    for (int rr = 0; rr < 8; ++rr) {
        const int row = row0 + rr;
        const int b = row / THW;
        const int* id = idx5 + (size_t)row * TOPK;
        const f16* base = Xs + (size_t)b * THW * 512;
        float4 m = make_float4(-FLT_MAX, -FLT_MAX, -FLT_MAX, -FLT_MAX);
#pragma unroll
        for (int i = 0; i < TOPK; ++i) {
            const f16* rp = base + (size_t)id[i] * 512 + lane * 4;
            const half4 h = *(const half4*)rp;
            const half4 l = *(const half4*)(rp + 256);
            m.x = fmaxf(m.x, (float)h.x + (float)l.x);
            m.y = fmaxf(m.y, (float)h.y + (float)l.y);
            m.z = fmaxf(m.z, (float)h.z + (float)l.z);
            m.w = fmaxf(m.w, (float)h.w + (float)l.w);
        }
        half4 ym; ym.x = (f16)m.x; ym.y = (f16)m.y; ym.z = (f16)m.z; ym.w = (f16)m.w;
        *(half4*)(yf + (size_t)row * CCH + lane * 4) = ym;
        s1x += m.x; s1y += m.y; s1z += m.z; s1w += m.w;
        s2x += m.x * m.x; s2y += m.y * m.y; s2z += m.z * m.z; s2w += m.w * m.w;
    }
    *(float4*)&ls[0][wid][lane * 4] = make_float4(s1x, s1y, s1z, s1w);
    *(float4*)&ls[1][wid][lane * 4] = make_float4(s2x, s2y, s2z, s2w);
    __syncthreads();
    const float a  = ls[0][0][tid] + ls[0][1][tid] + ls[0][2][tid] + ls[0][3][tid];
    const float b2 = ls[1][0][tid] + ls[1][1][tid] + ls[1][2][tid] + ls[1][3][tid];
    partial[(size_t)blockIdx.x * 512 + tid] = a;
    partial[(size_t)blockIdx.x * 512 + 256 + tid] = b2;
}

// ------------------------------------------------- 6. BN finalize -> scale/shift
__global__ __launch_bounds__(256)
void bn_final_kernel(const float* __restrict__ partial, const float* __restrict__ gamma,
                     const float* __restrict__ beta, float* __restrict__ ab) {
    const int c = blockIdx.x;
    const int tid = threadIdx.x;
    float s1 = 0, s2 = 0;
    for (int p = tid; p < 784; p += 256) {
        s1 += partial[(size_t)p * 512 + c];
        s2 += partial[(size_t)p * 512 + 256 + c];
    }
    __shared__ float r1[256], r2[256];
    r1[tid] = s1; r2[tid] = s2;
    __syncthreads();
    for (int off = 128; off > 0; off >>= 1) {
        if (tid < off) { r1[tid] += r1[tid + off]; r2[tid] += r2[tid + off]; }
        __syncthreads();
    }
    if (tid == 0) {
        const float inv_n = 1.0f / 25088.0f;
        const float mean = r1[0] * inv_n;
        const float var  = r2[0] * inv_n - mean * mean;
        const float a = gamma[c] / sqrtf(var + 1e-5f);
        ab[c] = a;
        ab[256 + c] = beta[c] - mean * a;
    }
}

// ------------------------------------------------- 7. relu(BN) -> 1x1 conv (f16 MFMA) + identity
// grid (196, 2): 128-row x 128-out tile, K=256 in 4 chunks of 64.
__global__ __launch_bounds__(256, 2)
void conv_f16_kernel(const f16* __restrict__ yf, const float* __restrict__ w,
                     const float* __restrict__ ab, const float* __restrict__ cb,
                     const float* __restrict__ x, float* __restrict__ out) {
    __shared__ __align__(16) f16 smem[2 * 128 * 64];   // 32 KB
    f16* As = smem;                // relu(bn(y)) tile [128 rows][64 ch]
    f16* Ws = smem + 8192;         // weights        [128 outs][64 ch]

    const int tid = threadIdx.x;
    const int lane = tid & 63, wid = tid >> 6;
    const int wr = (wid >> 1) * 64, wc = (wid & 1) * 64;
    const int lm = lane & 15, q = lane >> 4;
    const int lm7 = lm & 7;
    const int R0 = blockIdx.x * 128;
    const int o0 = blockIdx.y * 128;
    const int g8 = (tid & 7) * 8;          // channel sub-offset
    const int sr = tid >> 3;               // staging row 0..31 (+32p)

    f32x4 acc[4][4];
#pragma unroll
    for (int i = 0; i < 4; ++i)
#pragma unroll
        for (int j = 0; j < 4; ++j) acc[i][j] = (f32x4)0.0f;

    float cbv[4];
#pragma unroll
    for (int j = 0; j < 4; ++j) cbv[j] = cb[o0 + wc + 16 * j + lm];

    for (int kc = 0; kc < CCH; kc += 64) {
        const int cbase = kc + g8;
        const float4 sa0 = *(const float4*)(ab + cbase);
        const float4 sa1 = *(const float4*)(ab + cbase + 4);
        const float4 sb0 = *(const float4*)(ab + 256 + cbase);
        const float4 sb1 = *(const float4*)(ab + 256 + cbase + 4);
#pragma unroll
        for (int p = 0; p < 4; ++p) {
            const int r = sr + 32 * p;
            const half8 hv = *(const half8*)(yf + (size_t)(R0 + r) * CCH + cbase);
            half8 z;
            z[0] = (f16)fmaxf(fmaf((float)hv[0], sa0.x, sb0.x), 0.0f);
            z[1] = (f16)fmaxf(fmaf((float)hv[1], sa0.y, sb0.y), 0.0f);
            z[2] = (f16)fmaxf(fmaf((float)hv[2], sa0.z, sb0.z), 0.0f);
            z[3] = (f16)fmaxf(fmaf((float)hv[3], sa0.w, sb0.w), 0.0f);
            z[4] = (f16)fmaxf(fmaf((float)hv[4], sa1.x, sb1.x), 0.0f);
            z[5] = (f16)fmaxf(fmaf((float)hv[5], sa1.y, sb1.y), 0.0f);
            z[6] = (f16)fmaxf(fmaf((float)hv[6], sa1.z, sb1.z), 0.0f);
            z[7] = (f16)fmaxf(fmaf((float)hv[7], sa1.w, sb1.w), 0.0f);
            *(half8*)(As + r * 64 + (((tid & 7) ^ (r & 7)) * 8)) = z;
        }
#pragma unroll
        for (int p = 0; p < 4; ++p) {
            const int ol = sr + 32 * p;
            const float4 w0 = *(const float4*)(w + (size_t)(o0 + ol) * CCH + cbase);
            const float4 w1 = *(const float4*)(w + (size_t)(o0 + ol) * CCH + cbase + 4);
            half8 z;
            z[0] = (f16)w0.x; z[1] = (f16)w0.y; z[2] = (f16)w0.z; z[3] = (f16)w0.w;
            z[4] = (f16)w1.x; z[5] = (f16)w1.y; z[6] = (f16)w1.z; z[7] = (f16)w1.w;
            *(half8*)(Ws + ol * 64 + (((tid & 7) ^ (ol & 7)) * 8)) = z;
        }
        __syncthreads();
#pragma unroll
        for (int ks = 0; ks < 2; ++ks) {
            const int ku = (((4 * ks + q) ^ lm7) * 8);
            half8 av[4], bv[4];
#pragma unroll
            for (int i = 0; i < 4; ++i)
                av[i] = *(const half8*)(As + (wr + 16 * i + lm) * 64 + ku);
#pragma unroll
            for (int j = 0; j < 4; ++j)
                bv[j] = *(const half8*)(Ws + (wc + 16 * j + lm) * 64 + ku);
#pragma unroll
            for (int i = 0; i < 4; ++i)
#pragma unroll
                for (int j = 0; j < 4; ++j)
                    acc[i][j] = __builtin_amdgcn_mfma_f32_16x16x32_f16(av[i], bv[j], acc[i][j], 0, 0, 0);
        }
        __syncthreads();
    }
#pragma unroll
    for (int i = 0; i < 4; ++i) {
#pragma unroll
        for (int reg = 0; reg < 4; ++reg) {
            const int R = R0 + wr + 16 * i + 4 * q + reg;
            const int bs = R / HW;
            const int hw = R - bs * HW;
#pragma unroll
            for (int j = 0; j < 4; ++j) {
                const int o = o0 + wc + 16 * j + lm;
                const size_t oi = ((size_t)bs * CCH + o) * HW + hw;
                out[oi] = acc[i][j][reg] + cbv[j] + x[oi];
            }
        }
    }
}

// ------------------------------------------------- launch
extern "C" void kernel_launch(void* const* d_in, const int* in_sizes, int n_in,
                              void* d_out, int out_size, void* d_ws, size_t ws_size,
                              hipStream_t stream) {
    const float* x      = (const float*)d_in[0];
    const float* gamma  = (const float*)d_in[1];
    const float* beta   = (const float*)d_in[2];
    const float* conv_w = (const float*)d_in[3];
    const float* conv_b = (const float*)d_in[4];
    float* out = (float*)d_out;

    float* ws = (float*)d_ws;
    f16*   Xsp  = (f16*)ws;                            // [25088][512] halves = 6,422,528 f
    f16*   yf   = (f16*)(ws + 6422528);                // [25088][256] halves = 3,211,264 f
    float* rinv = ws + 9633792;                        // 25,088
    float* part = ws + 9658880;                        // 401,408
    float* ab   = ws + 10060288;                       // 512
    int*   idx5 = (int*)(ws + 10060800);               // 125,440 ints
    float* pval = ws + 10186240;                       // 25088*35 = 878,080
    int*   pidx = (int*)(ws + 11064320);               // 878,080 ints
    // total = 11,942,400 floats = 47.8 MB

    transpose_split_kernel<<<dim3(32, 25, 8), 256, 0, stream>>>(x, Xsp);
    rownorm_kernel<<<6272, 256, 0, stream>>>(Xsp, rinv);
    gram_mfma_kernel<<<dim3(49, 7, B_), 256, 0, stream>>>(Xsp, rinv, pval, pidx);
    merge_topk_kernel<<<98, 256, 0, stream>>>(pval, pidx, idx5);
    gather_bn_kernel<<<NROWS / 32, 256, 0, stream>>>(Xsp, idx5, yf, part);
    bn_final_kernel<<<256, 256, 0, stream>>>(part, gamma, beta, ab);
    conv_f16_kernel<<<dim3(NROWS / 128, 2), 256, 0, stream>>>(yf, conv_w, ab, conv_b, x, out);
}

// Round 6
// 536.923 us; speedup vs baseline: 1.4420x; 1.0263x over previous
//
#include <hip/hip_runtime.h>
#include <cfloat>

#define B_    4
#define SNIP  8
#define CCH   256
#define HW    784
#define THW   6272      // SNIP*HW
#define NROWS 25088     // B_*THW
#define TOPK  5

typedef _Float16 f16;
typedef f16   half8 __attribute__((ext_vector_type(8)));
typedef f16   half4 __attribute__((ext_vector_type(4)));
typedef float f32x4 __attribute__((ext_vector_type(4)));

// ---------------------------------------------------------------- utilities
__device__ __forceinline__ void ins5(float key, int idx, float tv[TOPK], int ti[TOPK]) {
    if (key > tv[4]) {
        if (key > tv[2]) {
            if (key > tv[1]) {
                tv[4] = tv[3]; ti[4] = ti[3];
                tv[3] = tv[2]; ti[3] = ti[2];
                tv[2] = tv[1]; ti[2] = ti[1];
                if (key > tv[0]) { tv[1] = tv[0]; ti[1] = ti[0]; tv[0] = key; ti[0] = idx; }
                else             { tv[1] = key;  ti[1] = idx; }
            } else {
                tv[4] = tv[3]; ti[4] = ti[3];
                tv[3] = tv[2]; ti[3] = ti[2];
                tv[2] = key;   ti[2] = idx;
            }
        } else {
            if (key > tv[3]) { tv[4] = tv[3]; ti[4] = ti[3]; tv[3] = key; ti[3] = idx; }
            else             { tv[4] = key;  ti[4] = idx; }
        }
    }
}

__device__ __forceinline__ void async16(const void* g, void* l) {
    __builtin_amdgcn_global_load_lds(
        (const __attribute__((address_space(1))) void*)g,
        (__attribute__((address_space(3))) void*)l, 16, 0, 0);
}

// ------------------------------------------------- 1. fused transpose + rownorm + f16 split
// block = (bs, p-tile of 32 rows) covering ALL 256 channels.
__global__ __launch_bounds__(256)
void transpose_norm_split_kernel(const float* __restrict__ x, f16* __restrict__ Xs,
                                 float* __restrict__ rinv) {
    __shared__ float T[256][33];          // [channel][row-local], +1 pad
    const int bs = blockIdx.x;            // 0..31
    const int p0 = blockIdx.y * 32;       // 25 tiles (last partial: 16 rows)
    const int b = bs >> 3, f = bs & 7;
    const int tid = threadIdx.x;

    // load phase: per pass, 8 channels x 32 rows
    const int pl = tid & 31, ch = tid >> 5;       // ch 0..7
    const int p = p0 + pl;
    if (p < HW) {
#pragma unroll
        for (int cc = 0; cc < 32; ++cc) {
            const int c = cc * 8 + ch;
            T[c][pl] = x[((size_t)bs * CCH + c) * HW + p];
        }
    }
    __syncthreads();

    const int rloc = tid >> 3, k = tid & 7;       // 32 rows x 8 channel-blocks
    const int gp = p0 + rloc;
    const size_t trow = (size_t)b * THW + (size_t)f * HW + gp;

    // row sum-of-squares: thread sums its 32 channels, 8-lane shuffle reduce
    float s = 0.0f;
    if (gp < HW) {
#pragma unroll
        for (int j = 0; j < 32; ++j) {
            const float v = T[k * 32 + j][rloc];
            s += v * v;
        }
    }
    s += __shfl_xor(s, 1, 64);
    s += __shfl_xor(s, 2, 64);
    s += __shfl_xor(s, 4, 64);
    if (k == 0 && gp < HW) rinv[trow] = 1.0f / sqrtf(s);

    // write phase: hi/lo half8 stores (16 B/lane)
    if (gp < HW) {
#pragma unroll
        for (int q = 0; q < 4; ++q) {
            half8 hv, lv;
#pragma unroll
            for (int j = 0; j < 8; ++j) {
                const float v = T[k * 32 + q * 8 + j][rloc];
                const f16 h = (f16)v;
                hv[j] = h;
                lv[j] = (f16)(v - (float)h);
            }
            *(half8*)(Xs + trow * 512 + k * 32 + q * 8) = hv;
            *(half8*)(Xs + trow * 512 + 256 + k * 32 + q * 8) = lv;
        }
    }
}

// ------------------------------------------------- 2. MFMA gram + partial top-5
// grid (49, 7, 4). Per block: 128-col block, 7 row-tiles of 128, virtual K=768
// (f16 split: segments A=[hi,lo,hi], B=[hi,hi,lo]). K-loop identical to the
// measured 403us r2 kernel; only LDS size (32KB) + launch bounds (3) changed.
__global__ __launch_bounds__(256, 3)
void gram_mfma_kernel(const f16* __restrict__ Xs, const float* __restrict__ rinv,
                      float* __restrict__ pval, int* __restrict__ pidx) {
    __shared__ __align__(16) char smem[32768];   // staging 32KB | merge 30KB (reused)
    f16* As = (f16*)smem;                 // [128][64] halves, unit-swizzled
    f16* Bs = As + 8192;

    const int tid = threadIdx.x;
    const int lane = tid & 63, wid = tid >> 6;
    const int wr = (wid >> 1) * 64, wc = (wid & 1) * 64;
    const int lm = lane & 15, q = lane >> 4;
    const int lm7 = lm & 7;
    const int b = blockIdx.z;
    const int j0 = blockIdx.x * 128;
    const int rg = blockIdx.y;
    const size_t bbase = (size_t)b * THW;
    const f16* Xb = Xs + bbase * 512;
    const float* rv = rinv + bbase;

    // staging lane map: row within pass, swizzled 16B-unit within row
    const int srow = tid >> 3;
    const int skk = (((tid & 7) ^ (srow & 7)) * 8);   // halves

    int fj[4];
#pragma unroll
    for (int j = 0; j < 4; ++j) fj[j] = (j0 + wc + 16 * j + lm) / HW;

    float tv[4][TOPK];
    int   ti[4][TOPK];
#pragma unroll
    for (int j = 0; j < 4; ++j)
#pragma unroll
        for (int s = 0; s < TOPK; ++s) { tv[j][s] = -FLT_MAX; ti[j][s] = 0; }

    const int segA[3] = {0, 256, 0};
    const int segB[3] = {0, 0, 256};

    for (int it = 0; it < 7; ++it) {
        const int t0 = (rg * 7 + it) * 128;
        f32x4 acc[4][4];
#pragma unroll
        for (int i = 0; i < 4; ++i)
#pragma unroll
            for (int j = 0; j < 4; ++j) acc[i][j] = (f32x4)0.0f;

        for (int cc = 0; cc < 12; ++cc) {
            const int seg = cc >> 2, k64 = (cc & 3) * 64;
            const int aoff = segA[seg] + k64 + skk;
            const int boff = segB[seg] + k64 + skk;
#pragma unroll
            for (int p = 0; p < 4; ++p)
                async16(Xb + (size_t)(t0 + srow + 32 * p) * 512 + aoff,
                        smem + wid * 1024 + p * 4096);
#pragma unroll
            for (int p = 0; p < 4; ++p)
                async16(Xb + (size_t)(j0 + srow + 32 * p) * 512 + boff,
                        smem + 16384 + wid * 1024 + p * 4096);
            __syncthreads();
#pragma unroll
            for (int ks = 0; ks < 2; ++ks) {
                const int ku = (((4 * ks + q) ^ lm7) * 8);   // swizzled unit, halves
                half8 av[4], bv[4];
#pragma unroll
                for (int i = 0; i < 4; ++i)
                    av[i] = *(const half8*)(As + (wr + 16 * i + lm) * 64 + ku);
#pragma unroll
                for (int j = 0; j < 4; ++j)
                    bv[j] = *(const half8*)(Bs + (wc + 16 * j + lm) * 64 + ku);
#pragma unroll
                for (int i = 0; i < 4; ++i)
#pragma unroll
                    for (int j = 0; j < 4; ++j)
                        acc[i][j] = __builtin_amdgcn_mfma_f32_16x16x32_f16(av[i], bv[j], acc[i][j], 0, 0, 0);
            }
            __syncthreads();
        }
        // epilogue: key = up * rinv[row]; mask same-frame; private top-5
#pragma unroll
        for (int i = 0; i < 4; ++i) {
            const int tb = t0 + wr + 16 * i + 4 * q;
            const f32x4 r4 = *(const f32x4*)(rv + tb);
#pragma unroll
            for (int reg = 0; reg < 4; ++reg) {
                const int t = tb + reg;
                const int ft = t / HW;
#pragma unroll
                for (int j = 0; j < 4; ++j) {
                    const float key = acc[i][j][reg] * r4[reg];
                    if (ft != fj[j]) ins5(key, t, tv[j], ti[j]);
                }
            }
        }
    }

    // merge: per column (128), 8 contributor slots (2 wave-pairs x 4 q) x 5 entries
    __syncthreads();
    float* Mv = (float*)smem;                        // [128][40] floats = 20KB
    unsigned short* Mi = (unsigned short*)(smem + 20480);   // [128][40] ushort = 10KB
    const int slot = (wid >> 1) * 4 + q;
#pragma unroll
    for (int j = 0; j < 4; ++j) {
        const int c128 = wc + 16 * j + lm;
#pragma unroll
        for (int s = 0; s < TOPK; ++s) {
            Mv[(c128 * 8 + slot) * TOPK + s] = tv[j][s];
            Mi[(c128 * 8 + slot) * TOPK + s] = (unsigned short)ti[j][s];
        }
    }
    __syncthreads();
    if (tid < 128) {
        float bv5[TOPK]; int bi5[TOPK];
#pragma unroll
        for (int s = 0; s < TOPK; ++s) { bv5[s] = -FLT_MAX; bi5[s] = 0; }
        for (int s = 0; s < 40; ++s) ins5(Mv[tid * 40 + s], (int)Mi[tid * 40 + s], bv5, bi5);
        const size_t base = ((bbase + j0 + tid) * 7 + rg) * TOPK;
#pragma unroll
        for (int s = 0; s < TOPK; ++s) { pval[base + s] = bv5[s]; pidx[base + s] = bi5[s]; }
    }
}

// ------------------------------------------------- 3. merge row-group partials
__global__ __launch_bounds__(256)
void merge_topk_kernel(const float* __restrict__ pval, const int* __restrict__ pidx,
                       int* __restrict__ idx5) {
    const int gid = blockIdx.x * 256 + threadIdx.x;   // 25088 columns
    float bv5[TOPK]; int bi5[TOPK];
#pragma unroll
    for (int s = 0; s < TOPK; ++s) { bv5[s] = -FLT_MAX; bi5[s] = 0; }
    const float* pv = pval + (size_t)gid * 35;
    const int* pi = pidx + (size_t)gid * 35;
    for (int s = 0; s < 35; ++s) ins5(pv[s], pi[s], bv5, bi5);
    int* op = idx5 + (size_t)gid * TOPK;
#pragma unroll
    for (int s = 0; s < TOPK; ++s) op[s] = bi5[s];
}

// ------------------------------------------------- 4. gather (from f16 pair) + max -> y f16 + BN partials
__global__ __launch_bounds__(256)
void gather_bn_kernel(const f16* __restrict__ Xs, const int* __restrict__ idx5,
                      f16* __restrict__ yf, float* __restrict__ partial) {
    __shared__ float ls[2][4][256];
    const int tid = threadIdx.x;
    const int wid = tid >> 6, lane = tid & 63;
    const int row0 = blockIdx.x * 32 + wid * 8;
    float s1x = 0, s1y = 0, s1z = 0, s1w = 0;
    float s2x = 0, s2y = 0, s2z = 0, s2w = 0;
    for (int rr = 0; rr < 8; ++rr) {
        const int row = row0 + rr;
        const int b = row / THW;
        const int* id = idx5 + (size_t)row * TOPK;
        const f16* base = Xs + (size_t)b * THW * 512;
        float4 m = make_float4(-FLT_MAX, -FLT_MAX, -FLT_MAX, -FLT_MAX);
#pragma unroll
        for (int i = 0; i < TOPK; ++i) {
            const f16* rp = base + (size_t)id[i] * 512 + lane * 4;
            const half4 h = *(const half4*)rp;
            const half4 l = *(const half4*)(rp + 256);
            m.x = fmaxf(m.x, (float)h.x + (float)l.x);
            m.y = fmaxf(m.y, (float)h.y + (float)l.y);
            m.z = fmaxf(m.z, (float)h.z + (float)l.z);
            m.w = fmaxf(m.w, (float)h.w + (float)l.w);
        }
        half4 ym; ym.x = (f16)m.x; ym.y = (f16)m.y; ym.z = (f16)m.z; ym.w = (f16)m.w;
        *(half4*)(yf + (size_t)row * CCH + lane * 4) = ym;
        s1x += m.x; s1y += m.y; s1z += m.z; s1w += m.w;
        s2x += m.x * m.x; s2y += m.y * m.y; s2z += m.z * m.z; s2w += m.w * m.w;
    }
    *(float4*)&ls[0][wid][lane * 4] = make_float4(s1x, s1y, s1z, s1w);
    *(float4*)&ls[1][wid][lane * 4] = make_float4(s2x, s2y, s2z, s2w);
    __syncthreads();
    const float a  = ls[0][0][tid] + ls[0][1][tid] + ls[0][2][tid] + ls[0][3][tid];
    const float b2 = ls[1][0][tid] + ls[1][1][tid] + ls[1][2][tid] + ls[1][3][tid];
    partial[(size_t)blockIdx.x * 512 + tid] = a;
    partial[(size_t)blockIdx.x * 512 + 256 + tid] = b2;
}

// ------------------------------------------------- 5. BN finalize -> scale/shift
__global__ __launch_bounds__(256)
void bn_final_kernel(const float* __restrict__ partial, const float* __restrict__ gamma,
                     const float* __restrict__ beta, float* __restrict__ ab) {
    const int c = blockIdx.x;
    const int tid = threadIdx.x;
    float s1 = 0, s2 = 0;
    for (int p = tid; p < 784; p += 256) {
        s1 += partial[(size_t)p * 512 + c];
        s2 += partial[(size_t)p * 512 + 256 + c];
    }
    __shared__ float r1[256], r2[256];
    r1[tid] = s1; r2[tid] = s2;
    __syncthreads();
    for (int off = 128; off > 0; off >>= 1) {
        if (tid < off) { r1[tid] += r1[tid + off]; r2[tid] += r2[tid + off]; }
        __syncthreads();
    }
    if (tid == 0) {
        const float inv_n = 1.0f / 25088.0f;
        const float mean = r1[0] * inv_n;
        const float var  = r2[0] * inv_n - mean * mean;
        const float a = gamma[c] / sqrtf(var + 1e-5f);
        ab[c] = a;
        ab[256 + c] = beta[c] - mean * a;
    }
}

// ------------------------------------------------- 6. relu(BN) -> 1x1 conv (f16 MFMA) + identity
// grid (196, 2): 128-row x 128-out tile, K=256 in 4 chunks of 64.
__global__ __launch_bounds__(256, 2)
void conv_f16_kernel(const f16* __restrict__ yf, const float* __restrict__ w,
                     const float* __restrict__ ab, const float* __restrict__ cb,
                     const float* __restrict__ x, float* __restrict__ out) {
    __shared__ __align__(16) f16 smem[2 * 128 * 64];   // 32 KB
    f16* As = smem;                // relu(bn(y)) tile [128 rows][64 ch]
    f16* Ws = smem + 8192;         // weights        [128 outs][64 ch]

    const int tid = threadIdx.x;
    const int lane = tid & 63, wid = tid >> 6;
    const int wr = (wid >> 1) * 64, wc = (wid & 1) * 64;
    const int lm = lane & 15, q = lane >> 4;
    const int lm7 = lm & 7;
    const int R0 = blockIdx.x * 128;
    const int o0 = blockIdx.y * 128;
    const int g8 = (tid & 7) * 8;          // channel sub-offset
    const int sr = tid >> 3;               // staging row 0..31 (+32p)

    f32x4 acc[4][4];
#pragma unroll
    for (int i = 0; i < 4; ++i)
#pragma unroll
        for (int j = 0; j < 4; ++j) acc[i][j] = (f32x4)0.0f;

    float cbv[4];
#pragma unroll
    for (int j = 0; j < 4; ++j) cbv[j] = cb[o0 + wc + 16 * j + lm];

    for (int kc = 0; kc < CCH; kc += 64) {
        const int cbase = kc + g8;
        const float4 sa0 = *(const float4*)(ab + cbase);
        const float4 sa1 = *(const float4*)(ab + cbase + 4);
        const float4 sb0 = *(const float4*)(ab + 256 + cbase);
        const float4 sb1 = *(const float4*)(ab + 256 + cbase + 4);
#pragma unroll
        for (int p = 0; p < 4; ++p) {
            const int r = sr + 32 * p;
            const half8 hv = *(const half8*)(yf + (size_t)(R0 + r) * CCH + cbase);
            half8 z;
            z[0] = (f16)fmaxf(fmaf((float)hv[0], sa0.x, sb0.x), 0.0f);
            z[1] = (f16)fmaxf(fmaf((float)hv[1], sa0.y, sb0.y), 0.0f);
            z[2] = (f16)fmaxf(fmaf((float)hv[2], sa0.z, sb0.z), 0.0f);
            z[3] = (f16)fmaxf(fmaf((float)hv[3], sa0.w, sb0.w), 0.0f);
            z[4] = (f16)fmaxf(fmaf((float)hv[4], sa1.x, sb1.x), 0.0f);
            z[5] = (f16)fmaxf(fmaf((float)hv[5], sa1.y, sb1.y), 0.0f);
            z[6] = (f16)fmaxf(fmaf((float)hv[6], sa1.z, sb1.z), 0.0f);
            z[7] = (f16)fmaxf(fmaf((float)hv[7], sa1.w, sb1.w), 0.0f);
            *(half8*)(As + r * 64 + (((tid & 7) ^ (r & 7)) * 8)) = z;
        }
#pragma unroll
        for (int p = 0; p < 4; ++p) {
            const int ol = sr + 32 * p;
            const float4 w0 = *(const float4*)(w + (size_t)(o0 + ol) * CCH + cbase);
            const float4 w1 = *(const float4*)(w + (size_t)(o0 + ol) * CCH + cbase + 4);
            half8 z;
            z[0] = (f16)w0.x; z[1] = (f16)w0.y; z[2] = (f16)w0.z; z[3] = (f16)w0.w;
            z[4] = (f16)w1.x; z[5] = (f16)w1.y; z[6] = (f16)w1.z; z[7] = (f16)w1.w;
            *(half8*)(Ws + ol * 64 + (((tid & 7) ^ (ol & 7)) * 8)) = z;
        }
        __syncthreads();
#pragma unroll
        for (int ks = 0; ks < 2; ++ks) {
            const int ku = (((4 * ks + q) ^ lm7) * 8);
            half8 av[4], bv[4];
#pragma unroll
            for (int i = 0; i < 4; ++i)
                av[i] = *(const half8*)(As + (wr + 16 * i + lm) * 64 + ku);
#pragma unroll
            for (int j = 0; j < 4; ++j)
                bv[j] = *(const half8*)(Ws + (wc + 16 * j + lm) * 64 + ku);
#pragma unroll
            for (int i = 0; i < 4; ++i)
#pragma unroll
                for (int j = 0; j < 4; ++j)
                    acc[i][j] = __builtin_amdgcn_mfma_f32_16x16x32_f16(av[i], bv[j], acc[i][j], 0, 0, 0);
        }
        __syncthreads();
    }
#pragma unroll
    for (int i = 0; i < 4; ++i) {
#pragma unroll
        for (int reg = 0; reg < 4; ++reg) {
            const int R = R0 + wr + 16 * i + 4 * q + reg;
            const int bs = R / HW;
            const int hw = R - bs * HW;
#pragma unroll
            for (int j = 0; j < 4; ++j) {
                const int o = o0 + wc + 16 * j + lm;
                const size_t oi = ((size_t)bs * CCH + o) * HW + hw;
                out[oi] = acc[i][j][reg] + cbv[j] + x[oi];
            }
        }
    }
}

// ------------------------------------------------- launch
extern "C" void kernel_launch(void* const* d_in, const int* in_sizes, int n_in,
                              void* d_out, int out_size, void* d_ws, size_t ws_size,
                              hipStream_t stream) {
    const float* x      = (const float*)d_in[0];
    const float* gamma  = (const float*)d_in[1];
    const float* beta   = (const float*)d_in[2];
    const float* conv_w = (const float*)d_in[3];
    const float* conv_b = (const float*)d_in[4];
    float* out = (float*)d_out;

    float* ws = (float*)d_ws;
    f16*   Xsp  = (f16*)ws;                            // [25088][512] halves = 6,422,528 f
    f16*   yf   = (f16*)(ws + 6422528);                // [25088][256] halves = 3,211,264 f
    float* rinv = ws + 9633792;                        // 25,088
    float* part = ws + 9658880;                        // 401,408
    float* ab   = ws + 10060288;                       // 512
    int*   idx5 = (int*)(ws + 10060800);               // 125,440 ints
    float* pval = ws + 10186240;                       // 25088*35 = 878,080
    int*   pidx = (int*)(ws + 11064320);               // 878,080 ints
    // total = 11,942,400 floats = 47.8 MB

    transpose_norm_split_kernel<<<dim3(32, 25), 256, 0, stream>>>(x, Xsp, rinv);
    gram_mfma_kernel<<<dim3(49, 7, B_), 256, 0, stream>>>(Xsp, rinv, pval, pidx);
    merge_topk_kernel<<<98, 256, 0, stream>>>(pval, pidx, idx5);
    gather_bn_kernel<<<NROWS / 32, 256, 0, stream>>>(Xsp, idx5, yf, part);
    bn_final_kernel<<<256, 256, 0, stream>>>(part, gamma, beta, ab);
    conv_f16_kernel<<<dim3(NROWS / 128, 2), 256, 0, stream>>>(yf, conv_w, ab, conv_b, x, out);
}